// Round 2
// baseline (90.733 us; speedup 1.0000x reference)
//
#include <hip/hip_runtime.h>
#include <math.h>

// QuanvolutionHybrid, algebraically collapsed.
//
// Reference only consumes <Z_0> of patch 0 per image. Circuit = per-image
// product state (RX embedding on 4 wires) followed by a FIXED unitary U
// (16 Rot + 16 CNOT, weights only). So:
//   <Z_0> = Tr[ M (rho0 x rho1 x rho2 x rho3) ],  M = U^dag Z_0 U
// with rho_w Bloch vector (0, -sin a_w, cos a_w). Expanding M in the Pauli
// basis, only {I,Y,Z}^4 strings survive -> 81 real coefficients mc[t],
// computed once per block from the weights. Per image:
//   <Z_0> = sum_t mc[t] * prod_w u_w[t_w],  u_w = (1, -sin a_w, cos a_w)
// The 1-qubit qfc chain collapses to q = beta*cos(z0) + gamma*sin(z0)
// (H = V^dag Z V is traceless Hermitian). Then Linear(1,10) + log_softmax.

struct c32 { float re, im; };

__device__ __forceinline__ c32 cmul(c32 a, c32 b) {
    return { fmaf(a.re, b.re, -a.im * b.im), fmaf(a.re, b.im, a.im * b.re) };
}
__device__ __forceinline__ c32 cadd(c32 a, c32 b) { return { a.re + b.re, a.im + b.im }; }
__device__ __forceinline__ c32 conjc(c32 a) { return { a.re, -a.im }; }

// PennyLane Rot(phi, theta, omega) = RZ(omega) RY(theta) RZ(phi)
__device__ __forceinline__ void make_rot(float phi, float th, float om,
                                         c32& u00, c32& u01, c32& u10, c32& u11) {
    float sh, ch; sincosf(th * 0.5f, &sh, &ch);
    float spo, cpo; sincosf((phi + om) * 0.5f, &spo, &cpo);
    float spm, cpm; sincosf((phi - om) * 0.5f, &spm, &cpm);
    u00 = {  cpo * ch, -spo * ch };
    u01 = { -cpm * sh, -spm * sh };
    u10 = {  cpm * sh, -spm * sh };
    u11 = {  cpo * ch,  spo * ch };
}

// Apply 2x2 gate on wire W (bit stride 8>>W) of a 16-amp state in registers.
template<int W>
__device__ __forceinline__ void apply1(c32 amp[16], c32 u00, c32 u01, c32 u10, c32 u11) {
    constexpr int s = 8 >> W;
    #pragma unroll
    for (int i = 0; i < 16; ++i) {
        if (i & s) continue;
        c32 a = amp[i], b = amp[i + s];
        amp[i]     = cadd(cmul(u00, a), cmul(u01, b));
        amp[i + s] = cadd(cmul(u10, a), cmul(u11, b));
    }
}

template<int C, int T>
__device__ __forceinline__ void cnot4(c32 amp[16]) {
    constexpr int sc = 8 >> C, st = 8 >> T;
    #pragma unroll
    for (int i = 0; i < 16; ++i) {
        if ((i & sc) && !(i & st)) {
            c32 tmp = amp[i]; amp[i] = amp[i | st]; amp[i | st] = tmp;
        }
    }
}

template<int W>
__device__ __forceinline__ void rot_apply(c32 amp[16], const float* p) {
    c32 a, b, c, d;
    make_rot(p[0], p[1], p[2], a, b, c, d);
    apply1<W>(amp, a, b, c, d);
}

__global__ __launch_bounds__(256)
void quanv_hybrid_kernel(const float* __restrict__ x,
                         const float* __restrict__ wq,    // [2,2,4,3]
                         const float* __restrict__ wfc,   // [3,3,1,3]
                         const float* __restrict__ Wout,  // [10,1]
                         const float* __restrict__ bout,  // [10]
                         float* __restrict__ out,         // [B,10]
                         int B)
{
    __shared__ c32 U[16][16];       // U[row k][col j]: column j = circuit|e_j>
    __shared__ c32 M[16][16];       // M[i][j] = sum_k conj(U[k][i]) z_k U[k][j]
    __shared__ float mc[81];        // Pauli {I,Y,Z}^4 coefficients of M
    __shared__ float fc_beta, fc_gamma;

    const int tid = threadIdx.x;

    // ---- Phase A: 16 columns of the fixed SEL unitary (wave 0, lanes 0-15)
    if (tid < 16) {
        c32 amp[16];
        #pragma unroll
        for (int i = 0; i < 16; ++i) amp[i] = { 0.f, 0.f };
        amp[tid].re = 1.f;
        #pragma unroll
        for (int al = 0; al < 4; ++al) {          // al = app*2 + l, ranges (1,2)
            const float* wp = wq + al * 12;
            rot_apply<0>(amp, wp + 0);
            rot_apply<1>(amp, wp + 3);
            rot_apply<2>(amp, wp + 6);
            rot_apply<3>(amp, wp + 9);
            if ((al & 1) == 0) {
                cnot4<0,1>(amp); cnot4<1,2>(amp); cnot4<2,3>(amp); cnot4<3,0>(amp);
            } else {
                cnot4<0,2>(amp); cnot4<1,3>(amp); cnot4<2,0>(amp); cnot4<3,1>(amp);
            }
        }
        #pragma unroll
        for (int k = 0; k < 16; ++k) U[k][tid] = amp[k];
    }

    // ---- Phase A': qfc constants (wave 1, runs concurrently with Phase A)
    if (tid == 64) {
        c32 v00 = {1.f,0.f}, v01 = {0.f,0.f}, v10 = {0.f,0.f}, v11 = {1.f,0.f};
        #pragma unroll
        for (int g = 0; g < 9; ++g) {
            const float* p = wfc + g * 3;
            c32 u00, u01, u10, u11;
            make_rot(p[0], p[1], p[2], u00, u01, u10, u11);
            c32 n00 = cadd(cmul(u00, v00), cmul(u01, v10));
            c32 n01 = cadd(cmul(u00, v01), cmul(u01, v11));
            c32 n10 = cadd(cmul(u10, v00), cmul(u11, v10));
            c32 n11 = cadd(cmul(u10, v01), cmul(u11, v11));
            v00 = n00; v01 = n01; v10 = n10; v11 = n11;
        }
        // H = V^dag Z V; beta = H00 (real, H traceless), gamma = Im H01
        fc_beta  = (v00.re*v00.re + v00.im*v00.im) - (v10.re*v10.re + v10.im*v10.im);
        c32 h01 = cadd(cmul(conjc(v00), v01),
                       c32{ -(conjc(v10).re*v11.re - conjc(v10).im*v11.im),
                            -(conjc(v10).re*v11.im + conjc(v10).im*v11.re) });
        fc_gamma = h01.im;
    }
    __syncthreads();

    // ---- Phase B: M = U^dag Z_0 U (256 threads, one entry each)
    {
        const int i = tid >> 4, j = tid & 15;
        c32 s = {0.f, 0.f};
        #pragma unroll
        for (int k = 0; k < 16; ++k) {
            c32 t = cmul(conjc(U[k][i]), U[k][j]);
            if (k < 8) { s.re += t.re; s.im += t.im; }
            else       { s.re -= t.re; s.im -= t.im; }
        }
        M[i][j] = s;
    }
    __syncthreads();

    // ---- Phase C: Pauli projection, t = d0*27+d1*9+d2*3+d3, digits I=0,Y=1,Z=2
    if (tid < 81) {
        const int t = tid;
        int d[4] = { t / 27, (t / 9) % 3, (t / 3) % 3, t % 3 };
        int xmask = 0;
        #pragma unroll
        for (int w = 0; w < 4; ++w) if (d[w] == 1) xmask |= (8 >> w);
        float acc = 0.f;   // Tr[P M] is real (both Hermitian); track complex anyway
        float acci = 0.f;
        for (int i = 0; i < 16; ++i) {
            const int j = i ^ xmask;
            float pre = 1.f, pim = 0.f;   // phase P_{i,j}
            #pragma unroll
            for (int w = 0; w < 4; ++w) {
                const int b = (i >> (3 - w)) & 1;
                if (d[w] == 2) {               // Z: diag(+1,-1)
                    if (b) { pre = -pre; pim = -pim; }
                } else if (d[w] == 1) {        // Y: (0,1)->-i, (1,0)->+i
                    float nre = b ? -pim :  pim;
                    float nim = b ?  pre : -pre;
                    pre = nre; pim = nim;
                }
            }
            c32 m = M[j][i];                   // Tr[PM] = sum_i P_{i,j} M_{j,i}
            acc  += pre * m.re - pim * m.im;
            acci += pre * m.im + pim * m.re;
            (void)acci;
        }
        mc[t] = acc * (1.f / 16.f);
    }
    __syncthreads();

    // ---- Phase D: per-image evaluation
    const int b = blockIdx.x * 256 + tid;
    if (b >= B) return;

    const float* xb = x + (size_t)b * 784;
    const float a0 = xb[0], a1 = xb[1], a2 = xb[28], a3 = xb[29];

    float u0[3], u1[3], u2[3], u3[3];
    { float s, c; sincosf(a0, &s, &c); u0[0]=1.f; u0[1]=-s; u0[2]=c; }
    { float s, c; sincosf(a1, &s, &c); u1[0]=1.f; u1[1]=-s; u1[2]=c; }
    { float s, c; sincosf(a2, &s, &c); u2[0]=1.f; u2[1]=-s; u2[2]=c; }
    { float s, c; sincosf(a3, &s, &c); u3[0]=1.f; u3[1]=-s; u3[2]=c; }

    float z0 = 0.f;
    #pragma unroll
    for (int t0 = 0; t0 < 3; ++t0) {
        float s1 = 0.f;
        #pragma unroll
        for (int t1 = 0; t1 < 3; ++t1) {
            float s2 = 0.f;
            #pragma unroll
            for (int t2 = 0; t2 < 3; ++t2) {
                const float* m = &mc[((t0 * 3 + t1) * 3 + t2) * 3];
                s2 = fmaf(m[0] + fmaf(m[1], u3[1], 0.f) + m[2] * u3[2], u2[t2], s2);
            }
            s1 = fmaf(s2, u1[t1], s1);
        }
        z0 = fmaf(s1, u0[t0], z0);
    }

    float sz, cz; sincosf(z0, &sz, &cz);
    const float q = fmaf(fc_beta, cz, fc_gamma * sz);

    float lg[10], mx = -1e30f;
    #pragma unroll
    for (int j = 0; j < 10; ++j) {
        lg[j] = fmaf(q, Wout[j], bout[j]);
        mx = fmaxf(mx, lg[j]);
    }
    float sum = 0.f;
    #pragma unroll
    for (int j = 0; j < 10; ++j) sum += expf(lg[j] - mx);
    const float lse = mx + logf(sum);

    float* ob = out + (size_t)b * 10;
    #pragma unroll
    for (int j = 0; j < 10; ++j) ob[j] = lg[j] - lse;
}

extern "C" void kernel_launch(void* const* d_in, const int* in_sizes, int n_in,
                              void* d_out, int out_size, void* d_ws, size_t ws_size,
                              hipStream_t stream) {
    const float* x    = (const float*)d_in[0];
    const float* wq   = (const float*)d_in[1];
    const float* wfc  = (const float*)d_in[2];
    const float* Wout = (const float*)d_in[3];
    const float* bout = (const float*)d_in[4];
    float* out = (float*)d_out;

    int B = in_sizes[0] / 784;  // 4096
    int blocks = (B + 255) / 256;
    quanv_hybrid_kernel<<<blocks, 256, 0, stream>>>(x, wq, wfc, Wout, bout, out, B);
}